// Round 4
// baseline (426.964 us; speedup 1.0000x reference)
//
#include <hip/hip_runtime.h>
#include <hip/hip_bf16.h>

typedef __bf16 bf16x8 __attribute__((ext_vector_type(8)));
typedef float f32x4 __attribute__((ext_vector_type(4)));
typedef unsigned int u32x4 __attribute__((ext_vector_type(4)));

#define WS 12
#define NTOK 144
#define RES 256
#define NHW 22
#define NWIN (4*NHW*NHW)
#define SCALE 0.17677669529663687f
#define XS 200   // x row stride (bf16): 400 B -> 2-way max on b128
#define QS 40    // q/k/v plane row stride (bf16): 80 B

#define WQ_ELEMS (576*192)
#define WP_ELEMS (192*192)
#define WS_NEED ((WQ_ELEMS + WP_ELEMS) * 2)

static __device__ __forceinline__ unsigned f2u(float f) {
    return (unsigned)__builtin_bit_cast(unsigned short, __float2bfloat16(f));
}
static __device__ __forceinline__ unsigned pk2(float a, float b) {
    return f2u(a) | (f2u(b) << 16);
}
static __device__ __forceinline__ bf16x8 ld8(const void* p) {
    return *(const bf16x8*)p;
}
static __device__ __forceinline__ bf16x8 wfrag(const float* p) {
    const float4* p4 = (const float4*)p;
    float4 lo = p4[0], hi = p4[1];
    u32x4 u = { pk2(lo.x, lo.y), pk2(lo.z, lo.w), pk2(hi.x, hi.y), pk2(hi.z, hi.w) };
    return __builtin_bit_cast(bf16x8, u);
}

__global__ __launch_bounds__(256) void conv_w(const float* __restrict__ wq,
                                              const float* __restrict__ wp,
                                              __hip_bfloat16* __restrict__ dst) {
    int i = blockIdx.x * 256 + threadIdx.x;
    if (i < WQ_ELEMS) dst[i] = __float2bfloat16(wq[i]);
    if (i < WP_ELEMS) dst[WQ_ELEMS + i] = __float2bfloat16(wp[i]);
}

template<bool WB>
__global__ __launch_bounds__(512, 2) void wsa_kernel(
    const float* __restrict__ x,
    const float* __restrict__ w_qkv,
    const float* __restrict__ w_proj,
    const __hip_bfloat16* __restrict__ wqb,
    const __hip_bfloat16* __restrict__ wpb,
    float* __restrict__ out)
{
    // union: xw [144][200] bf16 (57.6 KB)  ->  planes[9][144][40] bf16 (103.7 KB)
    //        -> stg [144][100] f32 (57.6 KB)
    __shared__ __align__(16) unsigned char smem[9 * NTOK * QS * 2];
    __hip_bfloat16 (* const xw)[XS]        = reinterpret_cast<__hip_bfloat16(*)[XS]>(smem);
    float          (* const stg)[100]      = reinterpret_cast<float(*)[100]>(smem);
    __hip_bfloat16 (* const planes)[NTOK][QS] =
        reinterpret_cast<__hip_bfloat16(*)[NTOK][QS]>(smem);

    const int tid  = threadIdx.x;
    const int lane = tid & 63;
    const int wv   = tid >> 6;      // 0..7
    const int col  = lane & 15;
    const int grp  = lane >> 4;     // 0..3
    const int mh   = wv & 1;        // m-half
    const int ng   = wv >> 1;       // n-group 0..3

    const int wid = blockIdx.x;
    const int b   = wid / (NHW * NHW);
    const int r0  = wid % (NHW * NHW);
    const int wh  = r0 / NHW;
    const int ww  = r0 % NHW;

    // ---- stage x window (reflect pad) into LDS bf16 [t][c] ----
    for (int u = tid; u < 24 * NTOK; u += 512) {   // u = c8*144 + t
        int c8 = u / NTOK;
        int t  = u - c8 * NTOK;
        int ty = t / WS, tx = t - ty * WS;
        int h = wh * WS + ty; if (h >= RES) h = 2 * RES - 2 - h;
        int w = ww * WS + tx; if (w >= RES) w = 2 * RES - 2 - w;
        const float* px = x + ((size_t)(b * 192 + c8 * 8) * RES + h) * RES + w;
        u32x4 uv;
        #pragma unroll
        for (int j = 0; j < 4; ++j)
            uv[j] = pk2(px[(size_t)(2 * j) * RES * RES], px[(size_t)(2 * j + 1) * RES * RES]);
        *(u32x4*)&xw[t][c8 * 8] = uv;
    }
    __syncthreads();

    // ---- A-cache fill: wave holds m-tiles {mh*4..mh*4+3} + mt8, all 6 k0 ----
    bf16x8 A[4][6], A8[6];
    const int mtbase = mh * 4;
    #pragma unroll
    for (int m = 0; m < 4; ++m)
        #pragma unroll
        for (int k0 = 0; k0 < 6; ++k0)
            A[m][k0] = ld8(&xw[(mtbase + m) * 16 + col][k0 * 32 + grp * 8]);
    #pragma unroll
    for (int k0 = 0; k0 < 6; ++k0)
        A8[k0] = ld8(&xw[128 + col][k0 * 32 + grp * 8]);
    __syncthreads();   // xw dead; planes may overwrite

    f32x4 pacc[5][3];
    #pragma unroll
    for (int i = 0; i < 5; ++i)
        #pragma unroll
        for (int m = 0; m < 3; ++m)
            pacc[i][m] = (f32x4){0.f, 0.f, 0.f, 0.f};

    // n-groups over 18 n-tiles: {0-4},{5-9},{10-13},{14-17}
    const int nstart = (ng < 2) ? ng * 5 : 10 + (ng - 2) * 4;
    const int ncnt   = (ng < 2) ? 5 : 4;

    for (int hp3 = 0; hp3 < 2; ++hp3) {            // 3 heads per pass
        // ---- qkv: nt = kind*6 + h3*2 + dh ----
        for (int nti = 0; nti < ncnt; ++nti) {
            const int nt   = nstart + nti;
            const int kind = nt / 6;
            const int h3   = (nt % 6) >> 1;
            const int dh   = nt & 1;
            const int rg   = kind * 192 + (hp3 * 3 + h3) * 32 + dh * 16 + col;
            const bool own8 = (dh == mh);
            f32x4 ac0{}, ac1{}, ac2{}, ac3{}, ac8{};
            #pragma unroll
            for (int k0 = 0; k0 < 6; ++k0) {
                const bf16x8 Bf = WB ? ld8(wqb + (size_t)rg * 192 + k0 * 32 + grp * 8)
                                     : wfrag(w_qkv + (size_t)rg * 192 + k0 * 32 + grp * 8);
                ac0 = __builtin_amdgcn_mfma_f32_16x16x32_bf16(A[0][k0], Bf, ac0, 0, 0, 0);
                ac1 = __builtin_amdgcn_mfma_f32_16x16x32_bf16(A[1][k0], Bf, ac1, 0, 0, 0);
                ac2 = __builtin_amdgcn_mfma_f32_16x16x32_bf16(A[2][k0], Bf, ac2, 0, 0, 0);
                ac3 = __builtin_amdgcn_mfma_f32_16x16x32_bf16(A[3][k0], Bf, ac3, 0, 0, 0);
                if (own8)
                    ac8 = __builtin_amdgcn_mfma_f32_16x16x32_bf16(A8[k0], Bf, ac8, 0, 0, 0);
            }
            __hip_bfloat16 (* const dst)[QS] = planes[kind * 3 + h3];
            const float qs = (kind == 0) ? SCALE : 1.f;
            #pragma unroll
            for (int r = 0; r < 4; ++r) {
                dst[(mtbase + 0) * 16 + grp * 4 + r][dh * 16 + col] = __float2bfloat16(ac0[r] * qs);
                dst[(mtbase + 1) * 16 + grp * 4 + r][dh * 16 + col] = __float2bfloat16(ac1[r] * qs);
                dst[(mtbase + 2) * 16 + grp * 4 + r][dh * 16 + col] = __float2bfloat16(ac2[r] * qs);
                dst[(mtbase + 3) * 16 + grp * 4 + r][dh * 16 + col] = __float2bfloat16(ac3[r] * qs);
            }
            if (own8) {
                #pragma unroll
                for (int r = 0; r < 4; ++r)
                    dst[128 + grp * 4 + r][dh * 16 + col] = __float2bfloat16(ac8[r] * qs);
            }
        }
        __syncthreads();

        // ---- coset attention: 27 tasks (h3, coset) over 8 waves ----
        for (int u = wv; u < 27; u += 8) {
            const int h3 = u / 9;
            const int cs = u % 9;
            __hip_bfloat16 (* const qP)[QS] = planes[0 + h3];
            __hip_bfloat16 (* const kP)[QS] = planes[3 + h3];
            __hip_bfloat16 (* const vP)[QS] = planes[6 + h3];
            const int ci = cs / 3, cj = cs % 3;
            const int tcol = (ci + 3 * (col >> 2)) * WS + cj + 3 * (col & 3);
            bf16x8 Kf = ld8(&kP[tcol][grp * 8]);
            bf16x8 Qf = ld8(&qP[tcol][grp * 8]);
            f32x4 S = {0.f, 0.f, 0.f, 0.f};
            S = __builtin_amdgcn_mfma_f32_16x16x32_bf16(Kf, Qf, S, 0, 0, 0);
            // lane holds S^T: key m = grp*4+r, query n = col
            float e[4]; float mx = -1e30f;
            #pragma unroll
            for (int r = 0; r < 4; ++r) {
                float s = (grp * 4 + r == col) ? -1e30f : S[r];
                e[r] = s;
                mx = fmaxf(mx, s);
            }
            mx = fmaxf(mx, __shfl_xor(mx, 16));
            mx = fmaxf(mx, __shfl_xor(mx, 32));
            float sum = 0.f;
            #pragma unroll
            for (int r = 0; r < 4; ++r) { e[r] = __expf(e[r] - mx); sum += e[r]; }
            sum += __shfl_xor(sum, 16);
            sum += __shfl_xor(sum, 32);
            const float inv = 1.f / sum;
            const unsigned w0 = pk2(e[0] * inv, e[1] * inv);
            const unsigned w1 = pk2(e[2] * inv, e[3] * inv);
            u32x4 pa = {0u, 0u, 0u, 0u};
            {
                const int sA = (col + 32 * grp) * 4;
                int q0 = __builtin_amdgcn_ds_bpermute(sA,      (int)w0);
                int q1 = __builtin_amdgcn_ds_bpermute(sA,      (int)w1);
                int q2 = __builtin_amdgcn_ds_bpermute(sA + 64, (int)w0);
                int q3 = __builtin_amdgcn_ds_bpermute(sA + 64, (int)w1);
                if (grp < 2) pa = (u32x4){(unsigned)q0, (unsigned)q1, (unsigned)q2, (unsigned)q3};
            }
            const bf16x8 PA = __builtin_bit_cast(bf16x8, pa);
            #pragma unroll
            for (int d0 = 0; d0 < 2; ++d0) {
                u32x4 vb = {0u, 0u, 0u, 0u};
                if (grp < 2) {
                    #pragma unroll
                    for (int j = 0; j < 8; j += 2) {
                        int m0 = grp * 8 + j, m1 = m0 + 1;
                        int t0 = (ci + 3 * (m0 >> 2)) * WS + cj + 3 * (m0 & 3);
                        int t1 = (ci + 3 * (m1 >> 2)) * WS + cj + 3 * (m1 & 3);
                        unsigned a  = __builtin_bit_cast(unsigned short, vP[t0][d0 * 16 + col]);
                        unsigned bb = __builtin_bit_cast(unsigned short, vP[t1][d0 * 16 + col]);
                        vb[j >> 1] = a | (bb << 16);
                    }
                }
                bf16x8 VB = __builtin_bit_cast(bf16x8, vb);
                f32x4 O = {0.f, 0.f, 0.f, 0.f};
                O = __builtin_amdgcn_mfma_f32_16x16x32_bf16(PA, VB, O, 0, 0, 0);
                #pragma unroll
                for (int r = 0; r < 4; ++r) {
                    int n = grp * 4 + r;
                    int t = (ci + 3 * (n >> 2)) * WS + cj + 3 * (n & 3);
                    qP[t][d0 * 16 + col] = __float2bfloat16(O[r]);  // ao (coset rows disjoint)
                }
            }
        }
        __syncthreads();

        // ---- proj partial: subtile u = (mg, oc); K = 96 (3 heads) ----
        #pragma unroll
        for (int i = 0; i < 5; ++i) {
            const int u = wv + 8 * i;
            if (u < 36) {
                const int oc = u % 12;
                const int mg = u / 12;
                #pragma unroll
                for (int h3 = 0; h3 < 3; ++h3) {
                    const int krow = (hp3 * 3 + h3) * 32 + grp * 8;
                    const bf16x8 Bf = WB ? ld8(wpb + (size_t)(oc * 16 + col) * 192 + krow)
                                         : wfrag(w_proj + (size_t)(oc * 16 + col) * 192 + krow);
                    #pragma unroll
                    for (int ml = 0; ml < 3; ++ml) {
                        const bf16x8 Af = ld8(&planes[h3][(mg * 3 + ml) * 16 + col][grp * 8]);
                        pacc[i][ml] = __builtin_amdgcn_mfma_f32_16x16x32_bf16(Af, Bf, pacc[i][ml], 0, 0, 0);
                    }
                }
            }
        }
        __syncthreads();
    }

    // ---- epilogue: stage f32 (overlay), coalesced write, two oc-halves ----
    for (int half = 0; half < 2; ++half) {
        if (half) __syncthreads();
        #pragma unroll
        for (int i = 0; i < 5; ++i) {
            const int u = wv + 8 * i;
            if (u < 36) {
                const int oc = u % 12;
                const int mg = u / 12;
                if (oc / 6 == half) {
                    #pragma unroll
                    for (int ml = 0; ml < 3; ++ml)
                        #pragma unroll
                        for (int r = 0; r < 4; ++r)
                            stg[(mg * 3 + ml) * 16 + grp * 4 + r][(oc % 6) * 16 + col] = pacc[i][ml][r];
                }
            }
        }
        __syncthreads();
        const int txo = tid % 12;
        const int u0  = tid / 12;    // 0..42
        if (u0 < 42) {
            for (int u = u0; u < 1152; u += 42) {     // u = oc_l*12 + ty
                int oc_l = u / 12, ty = u % 12;
                int h = wh * WS + ty, w = ww * WS + txo;
                if (h < RES && w < RES)
                    out[((size_t)(b * 192 + half * 96 + oc_l) * RES + h) * RES + w] = stg[ty * WS + txo][oc_l];
            }
        }
    }
}

extern "C" void kernel_launch(void* const* d_in, const int* in_sizes, int n_in,
                              void* d_out, int out_size, void* d_ws, size_t ws_size,
                              hipStream_t stream) {
    const float* x      = (const float*)d_in[0];
    const float* w_qkv  = (const float*)d_in[1];
    const float* w_proj = (const float*)d_in[2];
    float* out = (float*)d_out;
    if (ws_size >= (size_t)WS_NEED) {
        __hip_bfloat16* wqb = (__hip_bfloat16*)d_ws;
        __hip_bfloat16* wpb = wqb + WQ_ELEMS;
        conv_w<<<dim3((WQ_ELEMS + 255) / 256), dim3(256), 0, stream>>>(w_qkv, w_proj, wqb);
        wsa_kernel<true><<<dim3(NWIN), dim3(512), 0, stream>>>(x, w_qkv, w_proj, wqb, wpb, out);
    } else {
        wsa_kernel<false><<<dim3(NWIN), dim3(512), 0, stream>>>(x, w_qkv, w_proj, nullptr, nullptr, out);
    }
}

// Round 5
// 339.491 us; speedup vs baseline: 1.2577x; 1.2577x over previous
//
#include <hip/hip_runtime.h>
#include <hip/hip_bf16.h>

typedef __bf16 bf16x8 __attribute__((ext_vector_type(8)));
typedef float f32x4 __attribute__((ext_vector_type(4)));
typedef unsigned int u32x4 __attribute__((ext_vector_type(4)));

#define WSZ 12
#define NTOK 144
#define RES 256
#define NHW 22
#define NWIN (4*NHW*NHW)
#define SCALE 0.17677669529663687f
#define XS 200    // x row stride (bf16): 400 B, 16B-aligned, 2-way banks
#define QS 40     // q/k plane row stride (bf16): 80 B, 16B-aligned
#define VTS 152   // vT row stride (bf16): 304 B, 16B-aligned, 2-way banks

#define WQ_ELEMS (576*192)
#define WP_ELEMS (192*192)
#define WS_NEED ((WQ_ELEMS + WP_ELEMS) * 2)

// LDS byte offsets
#define OFF_Q  57600                     // q planes: 2 x [144][40] bf16
#define OFF_K  (57600 + 2*11520)         // k planes: 2 x [144][40] bf16
#define OFF_VT (57600 + 4*11520)         // vT: [2][32][152] bf16
#define SMEM_BYTES (OFF_VT + 2*32*VTS*2 + 128)   // 123,392 B

static __device__ __forceinline__ unsigned f2u(float f) {
    return (unsigned)__builtin_bit_cast(unsigned short, __float2bfloat16(f));
}
static __device__ __forceinline__ unsigned pk2(float a, float b) {
    return f2u(a) | (f2u(b) << 16);
}
static __device__ __forceinline__ bf16x8 ld8(const void* p) {
    return *(const bf16x8*)p;
}
static __device__ __forceinline__ bf16x8 wfrag(const float* p) {
    const float4* p4 = (const float4*)p;
    float4 lo = p4[0], hi = p4[1];
    u32x4 u = { pk2(lo.x, lo.y), pk2(lo.z, lo.w), pk2(hi.x, hi.y), pk2(hi.z, hi.w) };
    return __builtin_bit_cast(bf16x8, u);
}

__global__ __launch_bounds__(256) void conv_w(const float* __restrict__ wq,
                                              const float* __restrict__ wp,
                                              __hip_bfloat16* __restrict__ dst) {
    int i = blockIdx.x * 256 + threadIdx.x;
    if (i < WQ_ELEMS) dst[i] = __float2bfloat16(wq[i]);
    if (i < WP_ELEMS) dst[WQ_ELEMS + i] = __float2bfloat16(wp[i]);
}

template<bool WB>
__global__ __launch_bounds__(768, 3) void wsa_kernel(
    const float* __restrict__ x,
    const float* __restrict__ w_qkv,
    const float* __restrict__ w_proj,
    const __hip_bfloat16* __restrict__ wqb,
    const __hip_bfloat16* __restrict__ wpb,
    float* __restrict__ out)
{
    __shared__ __align__(16) unsigned char smem[SMEM_BYTES];
    __hip_bfloat16 (* const xw)[XS] = reinterpret_cast<__hip_bfloat16(*)[XS]>(smem);
    float          (* const stg)[100] = reinterpret_cast<float(*)[100]>(smem); // overlays xw (dead in epilogue)
    __hip_bfloat16* const vTp = reinterpret_cast<__hip_bfloat16*>(smem + OFF_VT);

    const int tid  = threadIdx.x;
    const int lane = tid & 63;
    const int wv   = tid >> 6;      // 0..11
    const int col  = lane & 15;
    const int grp  = lane >> 4;     // 0..3

    const int wid = blockIdx.x;
    const int b   = wid / (NHW * NHW);
    const int r0  = wid % (NHW * NHW);
    const int wh  = r0 / NHW;
    const int ww  = r0 % NHW;

    // ---- stage x window (reflect pad) into LDS bf16 [t][c] ----
    for (int u = tid; u < 24 * NTOK; u += 768) {   // u = c8*144 + t
        int c8 = u / NTOK;
        int t  = u - c8 * NTOK;
        int ty = t / WSZ, tx = t - ty * WSZ;
        int h = wh * WSZ + ty; if (h >= RES) h = 2 * RES - 2 - h;
        int w = ww * WSZ + tx; if (w >= RES) w = 2 * RES - 2 - w;
        const float* px = x + ((size_t)(b * 192 + c8 * 8) * RES + h) * RES + w;
        u32x4 uv;
        #pragma unroll
        for (int j = 0; j < 4; ++j)
            uv[j] = pk2(px[(size_t)(2 * j) * RES * RES], px[(size_t)(2 * j + 1) * RES * RES]);
        *(u32x4*)&xw[t][c8 * 8] = uv;
    }
    __syncthreads();

    f32x4 pacc[9];   // proj accumulators; wave owns oc-tile wv
    #pragma unroll
    for (int m = 0; m < 9; ++m) pacc[m] = (f32x4){0.f, 0.f, 0.f, 0.f};

    // qkv wave role: (mh, n6); n6 -> (kind, h2q); wave covers both dh halves
    const int mh   = wv & 1;
    const int n6   = wv >> 1;       // 0..5
    const int kind = n6 >> 1;       // 0=q 1=k 2=v
    const int h2q  = n6 & 1;
    const int mt0  = mh ? 4 : 0;
    const int nmt  = mh ? 5 : 4;    // mh=1 also owns mt8

    for (int hp = 0; hp < 3; ++hp) {
        // ---- qkv GEMM: m-half x (kind,h2q,dh both) ----
        {
            const int hh    = hp * 2 + h2q;
            const int rbase = kind * 192 + hh * 32;
            f32x4 acc[2][5];
            #pragma unroll
            for (int d = 0; d < 2; ++d)
                #pragma unroll
                for (int m = 0; m < 5; ++m) acc[d][m] = (f32x4){0.f, 0.f, 0.f, 0.f};
            #pragma unroll
            for (int k0 = 0; k0 < 6; ++k0) {
                const bf16x8 B0 = WB ? ld8(wqb + (size_t)(rbase + col) * 192 + k0 * 32 + grp * 8)
                                     : wfrag(w_qkv + (size_t)(rbase + col) * 192 + k0 * 32 + grp * 8);
                const bf16x8 B1 = WB ? ld8(wqb + (size_t)(rbase + 16 + col) * 192 + k0 * 32 + grp * 8)
                                     : wfrag(w_qkv + (size_t)(rbase + 16 + col) * 192 + k0 * 32 + grp * 8);
                #pragma unroll
                for (int m = 0; m < 5; ++m) {
                    if (m < nmt) {
                        const bf16x8 Af = ld8(&xw[(mt0 + m) * 16 + col][k0 * 32 + grp * 8]);
                        acc[0][m] = __builtin_amdgcn_mfma_f32_16x16x32_bf16(Af, B0, acc[0][m], 0, 0, 0);
                        acc[1][m] = __builtin_amdgcn_mfma_f32_16x16x32_bf16(Af, B1, acc[1][m], 0, 0, 0);
                    }
                }
            }
            const float qs = (kind == 0) ? SCALE : 1.f;
            if (kind < 2) {
                __hip_bfloat16 (* const pl)[QS] = reinterpret_cast<__hip_bfloat16(*)[QS]>(
                    smem + (kind == 0 ? OFF_Q : OFF_K) + h2q * 11520);
                #pragma unroll
                for (int m = 0; m < 5; ++m) if (m < nmt) {
                    #pragma unroll
                    for (int r = 0; r < 4; ++r) {
                        const int trow = (mt0 + m) * 16 + grp * 4 + r;
                        pl[trow][col]      = __float2bfloat16(acc[0][m][r] * qs);
                        pl[trow][16 + col] = __float2bfloat16(acc[1][m][r] * qs);
                    }
                }
            } else {
                #pragma unroll
                for (int m = 0; m < 5; ++m) if (m < nmt) {
                    #pragma unroll
                    for (int r = 0; r < 4; ++r) {
                        const int t  = (mt0 + m) * 16 + grp * 4 + r;
                        const int ti = t / WSZ, tj = t - ti * WSZ;
                        const int cs   = (ti % 3) * 3 + (tj % 3);
                        const int ctok = (ti / 3) * 4 + (tj / 3);
                        vTp[(size_t)(h2q * 32 + col) * VTS + cs * 16 + ctok]      = __float2bfloat16(acc[0][m][r]);
                        vTp[(size_t)(h2q * 32 + 16 + col) * VTS + cs * 16 + ctok] = __float2bfloat16(acc[1][m][r]);
                    }
                }
            }
        }
        __syncthreads();

        // ---- coset attention: 18 tasks (h2, coset) over 12 waves ----
        for (int u = wv; u < 18; u += 12) {
            const int h2 = u / 9;
            const int cs = u % 9;
            __hip_bfloat16 (* const qPl)[QS] = reinterpret_cast<__hip_bfloat16(*)[QS]>(smem + OFF_Q + h2 * 11520);
            __hip_bfloat16 (* const kPl)[QS] = reinterpret_cast<__hip_bfloat16(*)[QS]>(smem + OFF_K + h2 * 11520);
            const int ci = cs / 3, cj = cs % 3;
            const int tcol = (ci + 3 * (col >> 2)) * WSZ + cj + 3 * (col & 3);
            const bf16x8 Kf = ld8(&kPl[tcol][grp * 8]);
            const bf16x8 Qf = ld8(&qPl[tcol][grp * 8]);
            f32x4 S = {0.f, 0.f, 0.f, 0.f};
            S = __builtin_amdgcn_mfma_f32_16x16x32_bf16(Kf, Qf, S, 0, 0, 0);
            // lane holds S^T: key m = grp*4+r, query n = col
            float e[4]; float mx = -1e30f;
            #pragma unroll
            for (int r = 0; r < 4; ++r) {
                float s = (grp * 4 + r == col) ? -1e30f : S[r];
                e[r] = s;
                mx = fmaxf(mx, s);
            }
            mx = fmaxf(mx, __shfl_xor(mx, 16));
            mx = fmaxf(mx, __shfl_xor(mx, 32));
            float sum = 0.f;
            #pragma unroll
            for (int r = 0; r < 4; ++r) { e[r] = __expf(e[r] - mx); sum += e[r]; }
            sum += __shfl_xor(sum, 16);
            sum += __shfl_xor(sum, 32);
            const float inv = 1.f / sum;
            const unsigned w0 = pk2(e[0] * inv, e[1] * inv);
            const unsigned w1 = pk2(e[2] * inv, e[3] * inv);
            // P -> B-fragment: lane(col,grp<2) holds P[q=col][k=grp*8+j]
            u32x4 pa = {0u, 0u, 0u, 0u};
            {
                const int sA = (col + 32 * grp) * 4;
                int q0 = __builtin_amdgcn_ds_bpermute(sA,      (int)w0);
                int q1 = __builtin_amdgcn_ds_bpermute(sA,      (int)w1);
                int q2 = __builtin_amdgcn_ds_bpermute(sA + 64, (int)w0);
                int q3 = __builtin_amdgcn_ds_bpermute(sA + 64, (int)w1);
                if (grp < 2) pa = (u32x4){(unsigned)q0, (unsigned)q1, (unsigned)q2, (unsigned)q3};
            }
            const bf16x8 PB = __builtin_bit_cast(bf16x8, pa);
            // swapped PV: O^T = mfma(A=V^T, B=P); V^T A-frag is one b128 per d0
            #pragma unroll
            for (int d0 = 0; d0 < 2; ++d0) {
                const bf16x8 VA = ld8(&vTp[(size_t)(h2 * 32 + d0 * 16 + col) * VTS + cs * 16 + (grp & 1) * 8]);
                f32x4 O = {0.f, 0.f, 0.f, 0.f};
                O = __builtin_amdgcn_mfma_f32_16x16x32_bf16(VA, PB, O, 0, 0, 0);
                #pragma unroll
                for (int r = 0; r < 4; ++r)
                    qPl[tcol][d0 * 16 + grp * 4 + r] = __float2bfloat16(O[r]);  // ao (coset rows disjoint)
            }
        }
        __syncthreads();

        // ---- partial proj: K=64 (head pair); wave owns oc-tile wv ----
        {
            #pragma unroll
            for (int h2 = 0; h2 < 2; ++h2) {
                const int hh = hp * 2 + h2;
                const bf16x8 Bf = WB ? ld8(wpb + (size_t)(wv * 16 + col) * 192 + hh * 32 + grp * 8)
                                     : wfrag(w_proj + (size_t)(wv * 16 + col) * 192 + hh * 32 + grp * 8);
                __hip_bfloat16 (* const aoPl)[QS] = reinterpret_cast<__hip_bfloat16(*)[QS]>(smem + OFF_Q + h2 * 11520);
                #pragma unroll
                for (int mt = 0; mt < 9; ++mt) {
                    const bf16x8 Af = ld8(&aoPl[mt * 16 + col][grp * 8]);
                    pacc[mt] = __builtin_amdgcn_mfma_f32_16x16x32_bf16(Af, Bf, pacc[mt], 0, 0, 0);
                }
            }
        }
        __syncthreads();
    }

    // ---- output: stage f32 in (dead) x region, coalesced write, two oc-halves ----
    for (int half = 0; half < 2; ++half) {
        if (half) __syncthreads();
        if (wv >= half * 6 && wv < half * 6 + 6) {
            const int ocl = (wv - half * 6) * 16 + col;   // 0..95
            #pragma unroll
            for (int mt = 0; mt < 9; ++mt)
                #pragma unroll
                for (int r = 0; r < 4; ++r)
                    stg[mt * 16 + grp * 4 + r][ocl] = pacc[mt][r];
        }
        __syncthreads();
        const int txo = tid % 12;
        const int u0  = tid / 12;    // 0..63
        for (int it = 0; it < 18; ++it) {
            int u = u0 + it * 64;            // u = oc_l*12 + ty
            int oc_l = u / 12, ty = u % 12;
            int h = wh * WSZ + ty, w = ww * WSZ + txo;
            if (h < RES && w < RES)
                out[((size_t)(b * 192 + half * 96 + oc_l) * RES + h) * RES + w] = stg[ty * WSZ + txo][oc_l];
        }
    }
}

extern "C" void kernel_launch(void* const* d_in, const int* in_sizes, int n_in,
                              void* d_out, int out_size, void* d_ws, size_t ws_size,
                              hipStream_t stream) {
    const float* x      = (const float*)d_in[0];
    const float* w_qkv  = (const float*)d_in[1];
    const float* w_proj = (const float*)d_in[2];
    float* out = (float*)d_out;
    if (ws_size >= (size_t)WS_NEED) {
        __hip_bfloat16* wqb = (__hip_bfloat16*)d_ws;
        __hip_bfloat16* wpb = wqb + WQ_ELEMS;
        conv_w<<<dim3((WQ_ELEMS + 255) / 256), dim3(256), 0, stream>>>(w_qkv, w_proj, wqb);
        wsa_kernel<true><<<dim3(NWIN), dim3(768), 0, stream>>>(x, w_qkv, w_proj, wqb, wpb, out);
    } else {
        wsa_kernel<false><<<dim3(NWIN), dim3(768), 0, stream>>>(x, w_qkv, w_proj, nullptr, nullptr, out);
    }
}

// Round 6
// 291.885 us; speedup vs baseline: 1.4628x; 1.1631x over previous
//
#include <hip/hip_runtime.h>
#include <hip/hip_bf16.h>

typedef __bf16 bf16x8 __attribute__((ext_vector_type(8)));
typedef float f32x4 __attribute__((ext_vector_type(4)));
typedef unsigned int u32x4 __attribute__((ext_vector_type(4)));

#define WSZ 12
#define NTOK 144
#define RES 256
#define NHW 22
#define NWIN (4*NHW*NHW)
#define SCALE 0.17677669529663687f
#define XS 200    // x row stride (bf16): 400 B, 16B-aligned, 2-way banks
#define QS 40     // q/k/ao plane row stride (bf16): 80 B, 16B-aligned
#define VTS 152   // vT row stride (bf16): 304 B, 16B-aligned, 2-way banks
#define STS 148   // stg row stride (f32): 592 B, 16B-aligned

#define WQ_ELEMS (576*192)
#define WP_ELEMS (192*192)
#define WS_NEED ((WQ_ELEMS + WP_ELEMS) * 2)

// LDS byte offsets
#define OFF_Q  57600                       // q planes: 2 x [144][40] bf16
#define OFF_K  (OFF_Q + 2*11520)           // k planes: 2 x [144][40] bf16  (80640)
#define OFF_VT (OFF_K + 2*11520)           // vT: [2][32][152] bf16         (103680)
#define OFF_AO (OFF_VT + 2*32*VTS*2)       // ao planes: 2 x [144][40] bf16 (123136)
#define SMEM_BYTES (OFF_AO + 2*NTOK*QS*2)  // 146176 B
// stg overlays [0 .. 192*STS*4 = 113664) — xw/q/k/vT region, disjoint from ao

static __device__ __forceinline__ unsigned f2u(float f) {
    return (unsigned)__builtin_bit_cast(unsigned short, __float2bfloat16(f));
}
static __device__ __forceinline__ unsigned pk2(float a, float b) {
    return f2u(a) | (f2u(b) << 16);
}
static __device__ __forceinline__ bf16x8 ld8(const void* p) {
    return *(const bf16x8*)p;
}
static __device__ __forceinline__ bf16x8 wfrag(const float* p) {
    const float4* p4 = (const float4*)p;
    float4 lo = p4[0], hi = p4[1];
    u32x4 u = { pk2(lo.x, lo.y), pk2(lo.z, lo.w), pk2(hi.x, hi.y), pk2(hi.z, hi.w) };
    return __builtin_bit_cast(bf16x8, u);
}

__global__ __launch_bounds__(256) void conv_w(const float* __restrict__ wq,
                                              const float* __restrict__ wp,
                                              __hip_bfloat16* __restrict__ dst) {
    int i = blockIdx.x * 256 + threadIdx.x;
    if (i < WQ_ELEMS) dst[i] = __float2bfloat16(wq[i]);
    if (i < WP_ELEMS) dst[WQ_ELEMS + i] = __float2bfloat16(wp[i]);
}

template<bool WB>
__global__ __launch_bounds__(768, 3) void wsa_kernel(
    const float* __restrict__ x,
    const float* __restrict__ w_qkv,
    const float* __restrict__ w_proj,
    const __hip_bfloat16* __restrict__ wqb,
    const __hip_bfloat16* __restrict__ wpb,
    float* __restrict__ out)
{
    __shared__ __align__(16) unsigned char smem[SMEM_BYTES];
    __hip_bfloat16 (* const xw)[XS]  = reinterpret_cast<__hip_bfloat16(*)[XS]>(smem);
    float          (* const stg)[STS] = reinterpret_cast<float(*)[STS]>(smem);
    __hip_bfloat16* const vTp = reinterpret_cast<__hip_bfloat16*>(smem + OFF_VT);

    const int tid  = threadIdx.x;
    const int lane = tid & 63;
    const int wv   = tid >> 6;      // 0..11
    const int col  = lane & 15;
    const int grp  = lane >> 4;     // 0..3

    // XCD-aware swizzle (1936 % 8 == 0 -> bijective)
    const int wid0 = blockIdx.x;
    const int wid  = (wid0 & 7) * (NWIN / 8) + (wid0 >> 3);
    const int b    = wid / (NHW * NHW);
    const int r0   = wid % (NHW * NHW);
    const int wh   = r0 / NHW;
    const int ww   = r0 % NHW;

    // ---- stage x window (reflect pad) into LDS bf16 [t][c] ----
    for (int u = tid; u < 24 * NTOK; u += 768) {   // u = c8*144 + t
        int c8 = u / NTOK;
        int t  = u - c8 * NTOK;
        int ty = t / WSZ, tx = t - ty * WSZ;
        int h = wh * WSZ + ty; if (h >= RES) h = 2 * RES - 2 - h;
        int w = ww * WSZ + tx; if (w >= RES) w = 2 * RES - 2 - w;
        const float* px = x + ((size_t)(b * 192 + c8 * 8) * RES + h) * RES + w;
        u32x4 uv;
        #pragma unroll
        for (int j = 0; j < 4; ++j)
            uv[j] = pk2(px[(size_t)(2 * j) * RES * RES], px[(size_t)(2 * j + 1) * RES * RES]);
        *(u32x4*)&xw[t][c8 * 8] = uv;
    }
    __syncthreads();

    f32x4 pacc[9];   // proj accumulators; wave owns oc-tile wv
    #pragma unroll
    for (int m = 0; m < 9; ++m) pacc[m] = (f32x4){0.f, 0.f, 0.f, 0.f};

    // qkv wave role: (mh, n6); n6 -> (kind, h2q); wave covers both dh halves
    const int mh   = wv & 1;
    const int n6   = wv >> 1;       // 0..5
    const int kind = n6 >> 1;       // 0=q 1=k 2=v
    const int h2q  = n6 & 1;
    const int mt0  = mh ? 4 : 0;
    const int nmt  = mh ? 5 : 4;    // mh=1 also owns mt8

    auto do_proj = [&](int hpp) {
        #pragma unroll
        for (int h2 = 0; h2 < 2; ++h2) {
            const int hh = hpp * 2 + h2;
            const bf16x8 Bf = WB ? ld8(wpb + (size_t)(wv * 16 + col) * 192 + hh * 32 + grp * 8)
                                 : wfrag(w_proj + (size_t)(wv * 16 + col) * 192 + hh * 32 + grp * 8);
            const __hip_bfloat16 (* const aoPl)[QS] =
                reinterpret_cast<const __hip_bfloat16(*)[QS]>(smem + OFF_AO + h2 * 11520);
            #pragma unroll
            for (int mt = 0; mt < 9; ++mt) {
                const bf16x8 Af = ld8(&aoPl[mt * 16 + col][grp * 8]);
                pacc[mt] = __builtin_amdgcn_mfma_f32_16x16x32_bf16(Af, Bf, pacc[mt], 0, 0, 0);
            }
        }
    };

    for (int hp = 0; hp < 3; ++hp) {
        // ---- merged phase: qkv(hp) + proj(hp-1) ----
        {
            const int hh    = hp * 2 + h2q;
            const int rbase = kind * 192 + hh * 32;
            f32x4 acc[2][5];
            #pragma unroll
            for (int d = 0; d < 2; ++d)
                #pragma unroll
                for (int m = 0; m < 5; ++m) acc[d][m] = (f32x4){0.f, 0.f, 0.f, 0.f};
            #pragma unroll
            for (int k0 = 0; k0 < 6; ++k0) {
                const bf16x8 B0 = WB ? ld8(wqb + (size_t)(rbase + col) * 192 + k0 * 32 + grp * 8)
                                     : wfrag(w_qkv + (size_t)(rbase + col) * 192 + k0 * 32 + grp * 8);
                const bf16x8 B1 = WB ? ld8(wqb + (size_t)(rbase + 16 + col) * 192 + k0 * 32 + grp * 8)
                                     : wfrag(w_qkv + (size_t)(rbase + 16 + col) * 192 + k0 * 32 + grp * 8);
                #pragma unroll
                for (int m = 0; m < 5; ++m) {
                    if (m < nmt) {
                        const bf16x8 Af = ld8(&xw[(mt0 + m) * 16 + col][k0 * 32 + grp * 8]);
                        acc[0][m] = __builtin_amdgcn_mfma_f32_16x16x32_bf16(Af, B0, acc[0][m], 0, 0, 0);
                        acc[1][m] = __builtin_amdgcn_mfma_f32_16x16x32_bf16(Af, B1, acc[1][m], 0, 0, 0);
                    }
                }
            }
            const float qs = (kind == 0) ? SCALE : 1.f;
            if (kind < 2) {
                __hip_bfloat16 (* const pl)[QS] = reinterpret_cast<__hip_bfloat16(*)[QS]>(
                    smem + (kind == 0 ? OFF_Q : OFF_K) + h2q * 11520);
                #pragma unroll
                for (int m = 0; m < 5; ++m) if (m < nmt) {
                    #pragma unroll
                    for (int r = 0; r < 4; ++r) {
                        const int trow = (mt0 + m) * 16 + grp * 4 + r;
                        pl[trow][col]      = __float2bfloat16(acc[0][m][r] * qs);
                        pl[trow][16 + col] = __float2bfloat16(acc[1][m][r] * qs);
                    }
                }
            } else {
                #pragma unroll
                for (int m = 0; m < 5; ++m) if (m < nmt) {
                    #pragma unroll
                    for (int r = 0; r < 4; ++r) {
                        const int t  = (mt0 + m) * 16 + grp * 4 + r;
                        const int ti = t / WSZ, tj = t - ti * WSZ;
                        const int cs   = (ti % 3) * 3 + (tj % 3);
                        const int ctok = (ti / 3) * 4 + (tj / 3);
                        vTp[(size_t)(h2q * 32 + col) * VTS + cs * 16 + ctok]      = __float2bfloat16(acc[0][m][r]);
                        vTp[(size_t)(h2q * 32 + 16 + col) * VTS + cs * 16 + ctok] = __float2bfloat16(acc[1][m][r]);
                    }
                }
            }
            if (hp > 0) do_proj(hp - 1);
        }
        __syncthreads();

        // ---- coset attention: 18 tasks (h2, coset) over 12 waves; writes ao ----
        for (int u = wv; u < 18; u += 12) {
            const int h2 = u / 9;
            const int cs = u % 9;
            __hip_bfloat16 (* const qPl)[QS] = reinterpret_cast<__hip_bfloat16(*)[QS]>(smem + OFF_Q + h2 * 11520);
            __hip_bfloat16 (* const kPl)[QS] = reinterpret_cast<__hip_bfloat16(*)[QS]>(smem + OFF_K + h2 * 11520);
            __hip_bfloat16 (* const aoPl)[QS] = reinterpret_cast<__hip_bfloat16(*)[QS]>(smem + OFF_AO + h2 * 11520);
            const int ci = cs / 3, cj = cs % 3;
            const int tcol = (ci + 3 * (col >> 2)) * WSZ + cj + 3 * (col & 3);
            const bf16x8 Kf = ld8(&kPl[tcol][grp * 8]);
            const bf16x8 Qf = ld8(&qPl[tcol][grp * 8]);
            f32x4 S = {0.f, 0.f, 0.f, 0.f};
            S = __builtin_amdgcn_mfma_f32_16x16x32_bf16(Kf, Qf, S, 0, 0, 0);
            // lane holds S^T: key m = grp*4+r, query n = col
            float e[4]; float mx = -1e30f;
            #pragma unroll
            for (int r = 0; r < 4; ++r) {
                float s = (grp * 4 + r == col) ? -1e30f : S[r];
                e[r] = s;
                mx = fmaxf(mx, s);
            }
            mx = fmaxf(mx, __shfl_xor(mx, 16));
            mx = fmaxf(mx, __shfl_xor(mx, 32));
            float sum = 0.f;
            #pragma unroll
            for (int r = 0; r < 4; ++r) { e[r] = __expf(e[r] - mx); sum += e[r]; }
            sum += __shfl_xor(sum, 16);
            sum += __shfl_xor(sum, 32);
            const float inv = 1.f / sum;
            const unsigned w0 = pk2(e[0] * inv, e[1] * inv);
            const unsigned w1 = pk2(e[2] * inv, e[3] * inv);
            // P -> B-fragment: lane(col,grp<2) holds P[q=col][k=grp*8+j]
            u32x4 pa = {0u, 0u, 0u, 0u};
            {
                const int sA = (col + 32 * grp) * 4;
                int q0 = __builtin_amdgcn_ds_bpermute(sA,      (int)w0);
                int q1 = __builtin_amdgcn_ds_bpermute(sA,      (int)w1);
                int q2 = __builtin_amdgcn_ds_bpermute(sA + 64, (int)w0);
                int q3 = __builtin_amdgcn_ds_bpermute(sA + 64, (int)w1);
                if (grp < 2) pa = (u32x4){(unsigned)q0, (unsigned)q1, (unsigned)q2, (unsigned)q3};
            }
            const bf16x8 PB = __builtin_bit_cast(bf16x8, pa);
            // swapped PV: O^T = mfma(A=V^T, B=P)
            #pragma unroll
            for (int d0 = 0; d0 < 2; ++d0) {
                const bf16x8 VA = ld8(&vTp[(size_t)(h2 * 32 + d0 * 16 + col) * VTS + cs * 16 + (grp & 1) * 8]);
                f32x4 O = {0.f, 0.f, 0.f, 0.f};
                O = __builtin_amdgcn_mfma_f32_16x16x32_bf16(VA, PB, O, 0, 0, 0);
                #pragma unroll
                for (int r = 0; r < 4; ++r)
                    aoPl[tcol][d0 * 16 + grp * 4 + r] = __float2bfloat16(O[r]);
            }
        }
        __syncthreads();
    }

    // ---- final proj for last head pair ----
    do_proj(2);
    __syncthreads();

    // ---- epilogue: stage all 192 oc as f32 [oc][t] (overlays dead x/q/k/vT) ----
    {
        const int ocl = wv * 16 + col;
        #pragma unroll
        for (int mt = 0; mt < 9; ++mt) {
            float4 v4 = make_float4(pacc[mt][0], pacc[mt][1], pacc[mt][2], pacc[mt][3]);
            *(float4*)&stg[ocl][mt * 16 + grp * 4] = v4;
        }
    }
    __syncthreads();
    #pragma unroll
    for (int it = 0; it < 9; ++it) {
        int v = tid + it * 768;          // 0..6911 = (oc, ty, seg)
        int seg = v % 3;
        int rest = v / 3;
        int ty = rest % 12;
        int oc = rest / 12;
        int h  = wh * WSZ + ty;
        int w0 = ww * WSZ + seg * 4;
        if (h < RES && w0 < RES) {
            float4 val = *(const float4*)&stg[oc][ty * 12 + seg * 4];
            *(float4*)&out[((size_t)(b * 192 + oc) * RES + h) * RES + w0] = val;
        }
    }
}

extern "C" void kernel_launch(void* const* d_in, const int* in_sizes, int n_in,
                              void* d_out, int out_size, void* d_ws, size_t ws_size,
                              hipStream_t stream) {
    const float* x      = (const float*)d_in[0];
    const float* w_qkv  = (const float*)d_in[1];
    const float* w_proj = (const float*)d_in[2];
    float* out = (float*)d_out;
    if (ws_size >= (size_t)WS_NEED) {
        __hip_bfloat16* wqb = (__hip_bfloat16*)d_ws;
        __hip_bfloat16* wpb = wqb + WQ_ELEMS;
        conv_w<<<dim3((WQ_ELEMS + 255) / 256), dim3(256), 0, stream>>>(w_qkv, w_proj, wqb);
        wsa_kernel<true><<<dim3(NWIN), dim3(768), 0, stream>>>(x, w_qkv, w_proj, wqb, wpb, out);
    } else {
        wsa_kernel<false><<<dim3(NWIN), dim3(768), 0, stream>>>(x, w_qkv, w_proj, nullptr, nullptr, out);
    }
}